// Round 15
// baseline (427.730 us; speedup 1.0000x reference)
//
#include <hip/hip_runtime.h>
#include <hip/hip_bf16.h>

#define N_NODES 50000
#define N_EDGES 800000
#define HIDDEN  256
#define N_LAYERS 3
#define N_PAIRS 4096
#define N_LABEL 8192            // 2*N_PAIRS labeled rows
#define NPAD    50176           // 196*256, padded node count for the scan
#define SCAN_BLOCKS (NPAD / 256) // 196
#define WSZ (HIDDEN * HIDDEN)    // 65536 elems per weight matrix

typedef __bf16 bf16x8 __attribute__((ext_vector_type(8)));
typedef __bf16 bf16x4 __attribute__((ext_vector_type(4)));
typedef float  f32x4  __attribute__((ext_vector_type(4)));

__device__ __forceinline__ void load_lds16(const void* g, void* l) {
    __builtin_amdgcn_global_load_lds(
        (const __attribute__((address_space(1))) void*)g,
        (__attribute__((address_space(3))) void*)l, 16, 0, 0);
}

// ---------------------------------------------------------------------------
// FUSED layer GEMM — R15: BK=64 (8 barriers/block vs 16; each barrier drains
// vmcnt(0), the m97-style stall).  One launch does BOTH node linears:
//   blockIdx.z==0 : x0[r] = A[r]@Wt0^T (+deg*bD0) + bC0, stores SUPPRESSED
//                   on labeled rows (flags[r]!=0)
//   blockIdx.z==1 : x0[idx[r]] = A[idx[r]]@Wt1^T (+deg*bD1) + bC1
// Writes disjoint by construction -> race-free.
// 64x128 tile, BK=64, 4 waves stacked in m, 1x8 frags/wave, 2 k-steps/iter.
// LDS: As 8 KB + Bs 16 KB (~6 blocks/CU).
// ---------------------------------------------------------------------------
template <bool DEG_BIAS, bool A_FP32>
__global__ __launch_bounds__(256) void mfma_gemm_fused(
    const void* __restrict__ A_in,
    const __bf16* __restrict__ Wt0, const __bf16* __restrict__ Wt1,
    const float* __restrict__ bD0, const float* __restrict__ bD1,
    const float* __restrict__ bC0, const float* __restrict__ bC1,
    __bf16* __restrict__ Cout,
    const int* __restrict__ idx,     // pos (labeled rows)
    const int* __restrict__ offs,
    const int* __restrict__ flags,   // 1 = labeled row
    int M)
{
    const int role = blockIdx.z;
    if (role == 1 && blockIdx.x >= N_LABEL / 64) return;

    const __bf16* A   = (const __bf16*)A_in;
    const float*  A32 = (const float*)A_in;
    const __bf16* Wt  = role ? Wt1 : Wt0;
    const float*  bD  = role ? bD1 : bD0;
    const float*  bC  = role ? bC1 : bC0;

    __shared__ __bf16 As[64 * 64];    // 8 KB   [row][k], BK=64
    __shared__ __bf16 Bs[128 * 64];   // 16 KB  [n][k]
    __shared__ int s_idx[64];

    const int t    = threadIdx.x;
    const int lane = t & 63;
    const int wave = t >> 6;
    const int m0   = blockIdx.x * 64;
    const int n0   = blockIdx.y * 128;

    if (role == 1) {
        if (t < 64) s_idx[t] = idx[m0 + t];
        __syncthreads();
    }

    // A: 512 chunks (c>>3 = row, (c&7)*8 = k-col8), thread t owns c = t, 256+t
    // B: 1024 chunks, thread t owns c = r*256+t, r<4
    // LDS dest = chunk*16 B (wave-uniform base + lane*16: m104-safe)
    const __bf16* aptr[2];
    const float*  aptr32[2];
    #pragma unroll
    for (int r = 0; r < 2; ++r) {
        const int c     = r * 256 + t;
        const int arow  = c >> 3;
        const int acol8 = (c & 7) * 8;
        int node;
        if (role == 1) {
            node = s_idx[arow];
        } else {
            const int rg = m0 + arow;
            node = (rg < M) ? rg : (M - 1);   // clamp; stores guarded below
        }
        aptr[r]   = A   + (size_t)node * HIDDEN + acol8;
        aptr32[r] = A32 + (size_t)node * HIDDEN + acol8;
    }
    const __bf16* bptr[4];
    #pragma unroll
    for (int r = 0; r < 4; ++r) {
        const int c = r * 256 + t;
        bptr[r] = Wt + (size_t)(n0 + (c >> 3)) * HIDDEN + (c & 7) * 8;
    }

    f32x4 acc[8];
    #pragma unroll
    for (int i = 0; i < 8; ++i) acc[i] = (f32x4){0.f, 0.f, 0.f, 0.f};

    const int wm   = wave * 16;
    const int fm   = lane & 15;
    const int quad = lane >> 4;

    for (int k0 = 0; k0 < HIDDEN; k0 += 64) {
        __syncthreads();
        #pragma unroll
        for (int r = 0; r < 2; ++r) {
            if constexpr (A_FP32) {
                const float* ap = aptr32[r] + k0;
                const float4 u0 = *(const float4*)(ap);
                const float4 u1 = *(const float4*)(ap + 4);
                bf16x8 w = {(__bf16)u0.x, (__bf16)u0.y, (__bf16)u0.z, (__bf16)u0.w,
                            (__bf16)u1.x, (__bf16)u1.y, (__bf16)u1.z, (__bf16)u1.w};
                *(bf16x8*)(As + (size_t)(r * 256 + t) * 8) = w;
            } else {
                load_lds16(aptr[r] + k0, (void*)(As + (size_t)(r * 256 + t) * 8));
            }
        }
        #pragma unroll
        for (int r = 0; r < 4; ++r)
            load_lds16(bptr[r] + k0, (void*)(Bs + (size_t)(r * 256 + t) * 8));
        __syncthreads();   // drains vmcnt+lgkmcnt: staged data visible

        #pragma unroll
        for (int ks = 0; ks < 64; ks += 32) {
            const bf16x8 af = *(const bf16x8*)(As + (wm + fm) * 64 + ks + quad * 8);
            bf16x8 bfr[8];
            #pragma unroll
            for (int nt = 0; nt < 8; ++nt)
                bfr[nt] = *(const bf16x8*)(Bs + (nt * 16 + fm) * 64 + ks + quad * 8);
            #pragma unroll
            for (int nt = 0; nt < 8; ++nt)
                acc[nt] = __builtin_amdgcn_mfma_f32_16x16x32_bf16(
                    af, bfr[nt], acc[nt], 0, 0, 0);
        }
    }

    // epilogue: C/D layout col=lane&15, row=quad*4+reg (m89/m91-verified)
    float bd[8], bc[8];
    #pragma unroll
    for (int nt = 0; nt < 8; ++nt) {
        const int col = n0 + nt * 16 + fm;
        bd[nt] = DEG_BIAS ? bD[col] : 0.f;
        bc[nt] = bC[col];
    }

    #pragma unroll
    for (int rg = 0; rg < 4; ++rg) {
        const int rloc = wm + quad * 4 + rg;
        int orow;
        if (role == 1) {
            orow = s_idx[rloc];
        } else {
            orow = m0 + rloc;
            if (orow >= M) continue;
            if (flags[orow]) continue;     // labeled: z=1 writes this row
        }
        float bscale = 0.f;
        if constexpr (DEG_BIAS)
            bscale = (float)(offs[orow + 1] - offs[orow]);
        #pragma unroll
        for (int nt = 0; nt < 8; ++nt) {
            const int col = n0 + nt * 16 + fm;
            float v = acc[nt][rg];
            if constexpr (DEG_BIAS) v += bscale * bd[nt];
            v += bc[nt];
            Cout[(size_t)orow * HIDDEN + col] = (__bf16)v;
        }
    }
}

// ---------------------------------------------------------------------------
// Plain MFMA GEMM (product batch + final out GEMM).  64x128 tile, BK=32.
//   GATHER_A   : A-rows gathered via idx
//   DEG_VIA_IDX: A sequential/compact, deg via idx[rloc] (R13 NaN lesson)
// ---------------------------------------------------------------------------
template <bool GATHER_A, bool DEG_BIAS, bool DEG_VIA_IDX, bool OUT_BF16, bool PROD_BATCH>
__global__ __launch_bounds__(256) void mfma_gemm(
    const __bf16* __restrict__ A_in,
    const __bf16* __restrict__ Wt_in,
    const float* __restrict__ biasD,
    void* __restrict__ Cout_in,
    const int* __restrict__ idx,
    const int* __restrict__ offs,
    int M)
{
    const __bf16* A  = A_in;
    const __bf16* Wt = Wt_in;
    void* Cout = Cout_in;
    if constexpr (PROD_BATCH) {
        const int z = blockIdx.z;
        A    = A_in  + (size_t)(3 * (1 + (z >> 1)) + (z & 1)) * WSZ;
        Wt   = Wt_in + (size_t)(z >> 1) * WSZ;
        Cout = (void*)((__bf16*)Cout_in + (size_t)z * WSZ);
    }

    __shared__ __bf16 As[64 * 32];
    __shared__ __bf16 Bs[128 * 32];
    __shared__ int s_idx[64];

    const int t    = threadIdx.x;
    const int lane = t & 63;
    const int wave = t >> 6;
    const int m0   = blockIdx.x * 64;
    const int n0   = blockIdx.y * 128;

    if constexpr (GATHER_A || DEG_VIA_IDX) {
        if (t < 64) s_idx[t] = idx[m0 + t];
        __syncthreads();
    }

    const int arow  = t >> 2;
    const int acol8 = (t & 3) * 8;
    int anode;
    if constexpr (GATHER_A) {
        anode = s_idx[arow];
    } else {
        const int rg = m0 + arow;
        anode = (rg < M) ? rg : (M - 1);
    }
    const __bf16* aptr = A + (size_t)anode * HIDDEN + acol8;

    const __bf16* bptr[2];
    #pragma unroll
    for (int r = 0; r < 2; ++r) {
        const int c = r * 256 + t;
        bptr[r] = Wt + (size_t)(n0 + (c >> 2)) * HIDDEN + (c & 3) * 8;
    }

    f32x4 acc[8];
    #pragma unroll
    for (int i = 0; i < 8; ++i) acc[i] = (f32x4){0.f, 0.f, 0.f, 0.f};

    const int wm   = wave * 16;
    const int fm   = lane & 15;
    const int quad = lane >> 4;

    for (int k0 = 0; k0 < HIDDEN; k0 += 32) {
        __syncthreads();
        load_lds16(aptr + k0, (void*)(As + (size_t)t * 8));
        #pragma unroll
        for (int r = 0; r < 2; ++r)
            load_lds16(bptr[r] + k0, (void*)(Bs + (size_t)(r * 256 + t) * 8));
        __syncthreads();

        const bf16x8 af = *(const bf16x8*)(As + (wm + fm) * 32 + quad * 8);
        bf16x8 bfr[8];
        #pragma unroll
        for (int nt = 0; nt < 8; ++nt)
            bfr[nt] = *(const bf16x8*)(Bs + (nt * 16 + fm) * 32 + quad * 8);

        #pragma unroll
        for (int nt = 0; nt < 8; ++nt)
            acc[nt] = __builtin_amdgcn_mfma_f32_16x16x32_bf16(
                af, bfr[nt], acc[nt], 0, 0, 0);
    }

    float bd[8];
    #pragma unroll
    for (int nt = 0; nt < 8; ++nt)
        bd[nt] = DEG_BIAS ? biasD[n0 + nt * 16 + fm] : 0.f;

    #pragma unroll
    for (int rg = 0; rg < 4; ++rg) {
        const int rloc = wm + quad * 4 + rg;
        const int orow = m0 + rloc;
        if (!PROD_BATCH && orow >= M) continue;
        int dnode = orow;
        if constexpr (GATHER_A || DEG_VIA_IDX) dnode = s_idx[rloc];
        float bscale = 0.f;
        if constexpr (DEG_BIAS)
            bscale = (float)(offs[dnode + 1] - offs[dnode]);
        #pragma unroll
        for (int nt = 0; nt < 8; ++nt) {
            const int col = n0 + nt * 16 + fm;
            float v = acc[nt][rg];
            if constexpr (DEG_BIAS) v += bscale * bd[nt];
            if constexpr (OUT_BF16)
                ((__bf16*)Cout)[(size_t)orow * HIDDEN + col] = (__bf16)v;
            else
                ((float*)Cout)[(size_t)orow * HIDDEN + col] = v;
        }
    }
}

// ---------------------------------------------------------------------------
// Weight prep, 12 z-slices in ONE launch (unchanged from R14).
// ---------------------------------------------------------------------------
__global__ __launch_bounds__(256) void wconv_kernel(
    const float* __restrict__ f0_w, const float* __restrict__ f1_w,
    const float* __restrict__ conv_w, const float* __restrict__ conv_b,
    __bf16* __restrict__ wt_all, __bf16* __restrict__ cw_nt,
    float* __restrict__ q)
{
    const int z = blockIdx.z;
    const int kx = blockIdx.x * 32, nx = blockIdx.y * 32;
    const int tx = threadIdx.x, ty = threadIdx.y;

    if (z < 9) {
        const int layer = z / 3, which = z % 3;
        const float* W = ((which == 0) ? f0_w : (which == 1) ? f1_w : conv_w)
                         + (size_t)layer * WSZ;
        __bf16* T = wt_all + (size_t)z * WSZ;

        __shared__ float tile[32][33];
        for (int i = ty; i < 32; i += 8)
            tile[i][tx] = W[(size_t)(kx + i) * HIDDEN + nx + tx];
        __syncthreads();
        for (int i = ty; i < 32; i += 8)
            T[(size_t)(nx + i) * HIDDEN + kx + tx] = (__bf16)tile[tx][i];
    } else if (z < 11) {
        const int layer = z - 9;
        const float* W = conv_w + (size_t)layer * WSZ;
        __bf16* T = cw_nt + (size_t)layer * WSZ;
        for (int i = ty; i < 32; i += 8)
            T[(size_t)(kx + i) * HIDDEN + nx + tx] =
                (__bf16)W[(size_t)(kx + i) * HIDDEN + nx + tx];
    } else {
        if (blockIdx.x >= 4 || blockIdx.y != 0) return;
        const int zq = blockIdx.x;
        const int l = zq >> 1, branch = zq & 1;
        const float* cb = conv_b + (size_t)l * HIDDEN;
        const float* W  = (branch ? f1_w : f0_w) + (size_t)(l + 1) * WSZ;
        const int n = ty * 32 + tx;
        float s = 0.f;
        #pragma unroll 4
        for (int k = 0; k < HIDDEN; ++k)
            s += cb[k] * W[(size_t)k * HIDDEN + n];
        q[(size_t)zq * HIDDEN + n] = s;
    }
}

// ---------------------------------------------------------------------------
// CSR build: histogram (+labeled-row flags) -> fused scan -> fill
// ---------------------------------------------------------------------------
__global__ __launch_bounds__(256) void hist_kernel(
    const int* __restrict__ dst, const int* __restrict__ pos,
    int* __restrict__ counts, int* __restrict__ flags)
{
    int e = blockIdx.x * 256 + threadIdx.x;
    if (e < N_EDGES) atomicAdd(&counts[dst[e]], 1);
    if (e < N_LABEL) flags[pos[e]] = 1;   // benign dup writes
}

__device__ __forceinline__ int block_incl_scan(int v, int* s, int t)
{
    s[t] = v; __syncthreads();
    #pragma unroll
    for (int off = 1; off < 256; off <<= 1) {
        int add = (t >= off) ? s[t - off] : 0;
        __syncthreads();
        s[t] += add;
        __syncthreads();
    }
    return s[t];
}

// R15: single-dispatch exclusive scan (replaces scan1/scan2/scan3).
// All 196 blocks (×4 waves) are trivially co-resident on 256 CUs, so the
// counter spin cannot deadlock.  bsum publication + ctr + reads use
// AGENT-scope atomics — per-XCD L2s are NOT coherent (G16); plain volatile
// stores could be served stale cross-XCD.  bsum/ctr are zeroed by the
// launch-prefix memset every call (graph-replay safe).
__global__ __launch_bounds__(256) void scan_fused_kernel(
    const int* __restrict__ counts, int* __restrict__ offs,
    int* __restrict__ cursor, int* __restrict__ bsum, int* __restrict__ ctr)
{
    __shared__ int s[256];
    const int t = threadIdx.x;
    const int b = blockIdx.x;
    const int i = b * 256 + t;

    const int v    = counts[i];
    const int incl = block_incl_scan(v, s, t);
    const int excl = incl - v;
    const int total = s[255];        // block total (scan left s[] synced)
    __syncthreads();                 // everyone done reading s before reuse

    if (t == 0) {
        __hip_atomic_store(&bsum[b], total, __ATOMIC_RELEASE,
                           __HIP_MEMORY_SCOPE_AGENT);
        __hip_atomic_fetch_add(ctr, 1, __ATOMIC_ACQ_REL,
                               __HIP_MEMORY_SCOPE_AGENT);
        while (__hip_atomic_load(ctr, __ATOMIC_ACQUIRE,
                                 __HIP_MEMORY_SCOPE_AGENT) < SCAN_BLOCKS)
            __builtin_amdgcn_s_sleep(2);
    }
    __syncthreads();

    // base = sum of bsum[j], j < b  (parallel: thread j reads bsum[j])
    int pv = 0;
    if (t < b)
        pv = __hip_atomic_load(&bsum[t], __ATOMIC_ACQUIRE,
                               __HIP_MEMORY_SCOPE_AGENT);
    s[t] = pv; __syncthreads();
    #pragma unroll
    for (int off = 128; off >= 1; off >>= 1) {
        if (t < off) s[t] += s[t + off];
        __syncthreads();
    }
    const int o = excl + s[0];
    offs[i]   = o;
    cursor[i] = o;
}

__global__ __launch_bounds__(256) void fill_kernel(
    const int* __restrict__ src, const int* __restrict__ dst,
    int* __restrict__ cursor, int* __restrict__ src_sorted)
{
    int e = blockIdx.x * 256 + threadIdx.x;
    if (e < N_EDGES) {
        int p = atomicAdd(&cursor[dst[e]], 1);
        src_sorted[p] = src[e];
    }
}

// ---------------------------------------------------------------------------
// Pull-mode bf16 segment sum v5 — half-wave-per-dst + software pipelining.
// (R11-verified; structural random-gather ceiling ~57 us: 4 structures all
// land 56-65 us, FETCH pinned ~173 MB = 7x per-XCD L2 fill. Do not touch.)
// ---------------------------------------------------------------------------
template <bool COMPACT>
__global__ __launch_bounds__(256) void seg_sum5_kernel(
    const __bf16* __restrict__ x0,
    const int* __restrict__ srcs,
    const int* __restrict__ offs,
    const int* __restrict__ nodelist,
    __bf16* __restrict__ out)
{
    const int t    = threadIdx.x;
    const int wave = t >> 6;
    const int lane = t & 63;
    const int half = lane >> 5;
    const int li   = lane & 31;
    const int row  = blockIdx.x * 8 + wave * 2 + half;
    const int d    = COMPACT ? nodelist[row] : row;
    const int beg  = offs[d];
    const int deg  = offs[d + 1] - beg;
    const int hb   = half * 32;

    const __bf16* xs = x0 + li * 8;

    float a[8];
    #pragma unroll
    for (int k = 0; k < 8; ++k) a[k] = 0.f;

    for (int base = 0; base < deg; base += 32) {
        const int n = min(32, deg - base);
        int vs = 0;
        if (li < n) vs = srcs[beg + base + li];
        const int nv = n & ~3;

        bf16x8 c0, c1, c2, c3;
        if (nv) {
            const int s0 = __shfl(vs, hb + 0), s1 = __shfl(vs, hb + 1);
            const int s2 = __shfl(vs, hb + 2), s3 = __shfl(vs, hb + 3);
            c0 = *(const bf16x8*)(xs + (size_t)s0 * HIDDEN);
            c1 = *(const bf16x8*)(xs + (size_t)s1 * HIDDEN);
            c2 = *(const bf16x8*)(xs + (size_t)s2 * HIDDEN);
            c3 = *(const bf16x8*)(xs + (size_t)s3 * HIDDEN);
        }
        for (int j = 4; j + 4 <= nv; j += 4) {
            const int s0 = __shfl(vs, hb + j + 0), s1 = __shfl(vs, hb + j + 1);
            const int s2 = __shfl(vs, hb + j + 2), s3 = __shfl(vs, hb + j + 3);
            const bf16x8 n0 = *(const bf16x8*)(xs + (size_t)s0 * HIDDEN);
            const bf16x8 n1 = *(const bf16x8*)(xs + (size_t)s1 * HIDDEN);
            const bf16x8 n2 = *(const bf16x8*)(xs + (size_t)s2 * HIDDEN);
            const bf16x8 n3 = *(const bf16x8*)(xs + (size_t)s3 * HIDDEN);
            #pragma unroll
            for (int k = 0; k < 8; ++k)
                a[k] += (float)c0[k] + (float)c1[k] + (float)c2[k] + (float)c3[k];
            c0 = n0; c1 = n1; c2 = n2; c3 = n3;
        }
        if (nv) {
            #pragma unroll
            for (int k = 0; k < 8; ++k)
                a[k] += (float)c0[k] + (float)c1[k] + (float)c2[k] + (float)c3[k];
        }
        for (int j = nv; j < n; ++j) {
            const int s = __shfl(vs, hb + j);
            const bf16x8 v = *(const bf16x8*)(xs + (size_t)s * HIDDEN);
            #pragma unroll
            for (int k = 0; k < 8; ++k) a[k] += (float)v[k];
        }
    }

    bf16x8 o;
    #pragma unroll
    for (int k = 0; k < 8; ++k) o[k] = (__bf16)a[k];
    *(bf16x8*)(out + (size_t)row * HIDDEN + li * 8) = o;
}

extern "C" void kernel_launch(void* const* d_in, const int* in_sizes, int n_in,
                              void* d_out, int out_size, void* d_ws, size_t ws_size,
                              hipStream_t stream)
{
    const float* x       = (const float*)d_in[0];
    const float* f0_w    = (const float*)d_in[1];
    const float* f0_b    = (const float*)d_in[2];
    const float* f1_w    = (const float*)d_in[3];
    const float* f1_b    = (const float*)d_in[4];
    const float* conv_w  = (const float*)d_in[5];
    const float* conv_b  = (const float*)d_in[6];
    const int*   edge_src = (const int*)d_in[7];
    const int*   edge_dst = (const int*)d_in[8];
    const int*   pos      = (const int*)d_in[9];
    float* out = (float*)d_out;

    const size_t buf = (size_t)N_NODES * HIDDEN;   // 12.8M elems

    char* p = (char*)d_ws;
    __bf16* bufA   = (__bf16*)p; p += buf * 2;      // 25.6 MB
    __bf16* bufB   = (__bf16*)p; p += buf * 2;      // 25.6 MB
    __bf16* s_lbl  = (__bf16*)p; p += (size_t)N_LABEL * HIDDEN * 2;  // 4 MB
    __bf16* wt_all = (__bf16*)p; p += (size_t)9 * WSZ * 2;
    __bf16* prod   = (__bf16*)p; p += (size_t)4 * WSZ * 2;
    __bf16* cw_nt  = (__bf16*)p; p += (size_t)2 * WSZ * 2;
    float*  qv     = (float*)p;  p += (size_t)4 * HIDDEN * 4;
    // zeroed region: counts, flags, bsum, ctr (single memset)
    int* counts     = (int*)p;  p += NPAD * 4;     // reused as cursor
    int* flags      = (int*)p;  p += NPAD * 4;     // labeled-row bitmap
    int* bsum       = (int*)p;  p += 256 * 4;      // scan block totals
    int* ctr        = (int*)p;  p += 64 * 4;       // scan arrival counter
    int* offs       = (int*)p;  p += NPAD * 4;
    int* src_sorted = (int*)p;  p += (size_t)N_EDGES * 4;
    int* cursor = counts;       // counts dead after scan_fused reads them

    const int edge_blocks = (N_EDGES + 255) / 256;   // 3125

    // ---- CSR build + flags (one memset zeroes counts+flags+bsum+ctr) ----
    hipMemsetAsync(counts, 0, (2 * NPAD + 320) * sizeof(int), stream);
    hist_kernel<<<edge_blocks, 256, 0, stream>>>(edge_dst, pos, counts, flags);
    scan_fused_kernel<<<SCAN_BLOCKS, 256, 0, stream>>>(
        counts, offs, cursor, bsum, ctr);
    fill_kernel<<<edge_blocks, 256, 0, stream>>>(edge_src, edge_dst, cursor, src_sorted);

    // ---- weight prep: transpose (9) + straight Cw (2) + qprod, one launch ----
    wconv_kernel<<<dim3(8, 8, 12), dim3(32, 8), 0, stream>>>(
        f0_w, f1_w, conv_w, conv_b, wt_all, cw_nt, qv);

    // all 4 products prod_t[z] = (Cw_l · F_{l+1})^T in ONE batched launch
    mfma_gemm<false, false, false, true, true><<<dim3(4, 2, 4), 256, 0, stream>>>(
        wt_all, cw_nt, nullptr, prod, nullptr, nullptr, HIDDEN);

    const dim3 fused_grid(782, 2, 2);   // z=0 full (store-suppressed), z=1 label
    const dim3 lbl_grid(128, 2);

    __bf16* cur = bufA;              // S buffer (layer-0 GEMMs read x fp32)
    __bf16* tmp = bufB;

    for (int l = 0; l < N_LAYERS; ++l) {
        const float* B0 = f0_b + (size_t)l * HIDDEN;
        const float* B1 = f1_b + (size_t)l * HIDDEN;

        if (l == 0) {
            // x0 = x@F0_0+b0 (all, minus labeled) ∪ x@F1_0+b1 (labeled)
            mfma_gemm_fused<false, true><<<fused_grid, 256, 0, stream>>>(
                x, wt_all + 0 * WSZ, wt_all + 1 * WSZ,
                nullptr, nullptr, B0, B1, tmp, pos, offs, flags, N_NODES);
        } else {
            // x0 = S@(Cw·F0_l)+deg*q0+b0 ∪ S@(Cw·F1_l)+deg*q1+b1 (folded conv)
            const int z0 = (l - 1) * 2;
            mfma_gemm_fused<true, false><<<fused_grid, 256, 0, stream>>>(
                cur, prod + (size_t)z0 * WSZ, prod + (size_t)(z0 + 1) * WSZ,
                qv + (size_t)z0 * HIDDEN, qv + (size_t)(z0 + 1) * HIDDEN,
                B0, B1, tmp, pos, offs, flags, N_NODES);
        }

        if (l < N_LAYERS - 1) {
            // S = segment_sum(x0[src]) at ALL nodes (tmp -> cur)
            seg_sum5_kernel<false><<<N_NODES / 8, 256, 0, stream>>>(
                tmp, src_sorted, offs, nullptr, cur);
        } else {
            // S only at labeled dst nodes (tmp -> s_lbl, compact pos order)
            seg_sum5_kernel<true><<<N_LABEL / 8, 256, 0, stream>>>(
                tmp, src_sorted, offs, pos, s_lbl);
            // out[i] = S_lbl[i] @ Cw_2 + deg[pos[i]]*cb_2  -> d_out (fp32)
            // A sequential/compact (s_lbl), deg via idx (R13 lesson)
            mfma_gemm<false, true, true, false, false><<<lbl_grid, 256, 0, stream>>>(
                s_lbl, wt_all + (size_t)(2 * 3 + 2) * WSZ,
                conv_b + (size_t)2 * HIDDEN, out, pos, offs, N_LABEL);
        }
    }
}

// Round 16
// 424.237 us; speedup vs baseline: 1.0082x; 1.0082x over previous
//
#include <hip/hip_runtime.h>
#include <hip/hip_bf16.h>

#define N_NODES 50000
#define N_EDGES 800000
#define HIDDEN  256
#define N_LAYERS 3
#define N_PAIRS 4096
#define N_LABEL 8192            // 2*N_PAIRS labeled rows
#define NPAD    50176           // 196*256, padded node count for the scan
#define SCAN_BLOCKS (NPAD / 256) // 196
#define WSZ (HIDDEN * HIDDEN)    // 65536 elems per weight matrix

typedef __bf16 bf16x8 __attribute__((ext_vector_type(8)));
typedef __bf16 bf16x4 __attribute__((ext_vector_type(4)));
typedef float  f32x4  __attribute__((ext_vector_type(4)));

__device__ __forceinline__ void load_lds16(const void* g, void* l) {
    __builtin_amdgcn_global_load_lds(
        (const __attribute__((address_space(1))) void*)g,
        (__attribute__((address_space(3))) void*)l, 16, 0, 0);
}

// ---------------------------------------------------------------------------
// FUSED layer GEMM — BK=32 (R16: reverted from R15's BK=64; 24 KB LDS cut
// blocks/CU 13->6 and lost more to reduced latency-hiding than 8 fewer
// barriers gained — the m132 lesson).  One launch does BOTH node linears:
//   blockIdx.z==0 : x0[r] = A[r]@Wt0^T (+deg*bD0) + bC0, stores SUPPRESSED
//                   on labeled rows (flags[r]!=0)
//   blockIdx.z==1 : x0[idx[r]] = A[idx[r]]@Wt1^T (+deg*bD1) + bC1
// Writes disjoint by construction -> race-free.
// 64x128 tile, 4 waves stacked in m, 1x8 frags/wave. LDS 12.3 KB.
// ---------------------------------------------------------------------------
template <bool DEG_BIAS, bool A_FP32>
__global__ __launch_bounds__(256) void mfma_gemm_fused(
    const void* __restrict__ A_in,
    const __bf16* __restrict__ Wt0, const __bf16* __restrict__ Wt1,
    const float* __restrict__ bD0, const float* __restrict__ bD1,
    const float* __restrict__ bC0, const float* __restrict__ bC1,
    __bf16* __restrict__ Cout,
    const int* __restrict__ idx,     // pos (labeled rows)
    const int* __restrict__ offs,
    const int* __restrict__ flags,   // 1 = labeled row
    int M)
{
    const int role = blockIdx.z;
    if (role == 1 && blockIdx.x >= N_LABEL / 64) return;

    const __bf16* A   = (const __bf16*)A_in;
    const float*  A32 = (const float*)A_in;
    const __bf16* Wt  = role ? Wt1 : Wt0;
    const float*  bD  = role ? bD1 : bD0;
    const float*  bC  = role ? bC1 : bC0;

    __shared__ __bf16 As[64 * 32];    // 4 KB
    __shared__ __bf16 Bs[128 * 32];   // 8 KB
    __shared__ int s_idx[64];

    const int t    = threadIdx.x;
    const int lane = t & 63;
    const int wave = t >> 6;
    const int m0   = blockIdx.x * 64;
    const int n0   = blockIdx.y * 128;

    if (role == 1) {
        if (t < 64) s_idx[t] = idx[m0 + t];
        __syncthreads();
    }

    // A staging: chunk t; row=t>>2, col8=(t&3)*8. B: chunks r*256+t.
    // LDS dest = chunk*16 B (wave-uniform base + lane*16: m104-safe)
    const int arow  = t >> 2;
    const int acol8 = (t & 3) * 8;
    int anode;
    if (role == 1) {
        anode = s_idx[arow];
    } else {
        const int rg = m0 + arow;
        anode = (rg < M) ? rg : (M - 1);   // clamp; stores guarded below
    }
    const __bf16* aptr   = A   + (size_t)anode * HIDDEN + acol8;
    const float*  aptr32 = A32 + (size_t)anode * HIDDEN + acol8;

    const __bf16* bptr[2];
    #pragma unroll
    for (int r = 0; r < 2; ++r) {
        const int c = r * 256 + t;
        bptr[r] = Wt + (size_t)(n0 + (c >> 2)) * HIDDEN + (c & 3) * 8;
    }

    f32x4 acc[8];
    #pragma unroll
    for (int i = 0; i < 8; ++i) acc[i] = (f32x4){0.f, 0.f, 0.f, 0.f};

    const int wm   = wave * 16;
    const int fm   = lane & 15;
    const int quad = lane >> 4;

    for (int k0 = 0; k0 < HIDDEN; k0 += 32) {
        __syncthreads();
        if constexpr (A_FP32) {
            const float* ap = aptr32 + k0;
            const float4 u0 = *(const float4*)(ap);
            const float4 u1 = *(const float4*)(ap + 4);
            bf16x8 w = {(__bf16)u0.x, (__bf16)u0.y, (__bf16)u0.z, (__bf16)u0.w,
                        (__bf16)u1.x, (__bf16)u1.y, (__bf16)u1.z, (__bf16)u1.w};
            *(bf16x8*)(As + (size_t)t * 8) = w;
        } else {
            load_lds16(aptr + k0, (void*)(As + (size_t)t * 8));
        }
        #pragma unroll
        for (int r = 0; r < 2; ++r)
            load_lds16(bptr[r] + k0, (void*)(Bs + (size_t)(r * 256 + t) * 8));
        __syncthreads();   // drains vmcnt+lgkmcnt: staged data visible

        const bf16x8 af = *(const bf16x8*)(As + (wm + fm) * 32 + quad * 8);
        bf16x8 bfr[8];
        #pragma unroll
        for (int nt = 0; nt < 8; ++nt)
            bfr[nt] = *(const bf16x8*)(Bs + (nt * 16 + fm) * 32 + quad * 8);

        #pragma unroll
        for (int nt = 0; nt < 8; ++nt)
            acc[nt] = __builtin_amdgcn_mfma_f32_16x16x32_bf16(
                af, bfr[nt], acc[nt], 0, 0, 0);
    }

    // epilogue: C/D layout col=lane&15, row=quad*4+reg (m89/m91-verified)
    float bd[8], bc[8];
    #pragma unroll
    for (int nt = 0; nt < 8; ++nt) {
        const int col = n0 + nt * 16 + fm;
        bd[nt] = DEG_BIAS ? bD[col] : 0.f;
        bc[nt] = bC[col];
    }

    #pragma unroll
    for (int rg = 0; rg < 4; ++rg) {
        const int rloc = wm + quad * 4 + rg;
        int orow;
        if (role == 1) {
            orow = s_idx[rloc];
        } else {
            orow = m0 + rloc;
            if (orow >= M) continue;
            if (flags[orow]) continue;     // labeled: z=1 writes this row
        }
        float bscale = 0.f;
        if constexpr (DEG_BIAS)
            bscale = (float)(offs[orow + 1] - offs[orow]);
        #pragma unroll
        for (int nt = 0; nt < 8; ++nt) {
            const int col = n0 + nt * 16 + fm;
            float v = acc[nt][rg];
            if constexpr (DEG_BIAS) v += bscale * bd[nt];
            v += bc[nt];
            Cout[(size_t)orow * HIDDEN + col] = (__bf16)v;
        }
    }
}

// ---------------------------------------------------------------------------
// Plain MFMA GEMM (product batch + final out GEMM).  64x128 tile, BK=32.
//   GATHER_A   : A-rows gathered via idx
//   DEG_VIA_IDX: A sequential/compact, deg via idx[rloc] (R13 NaN lesson)
// ---------------------------------------------------------------------------
template <bool GATHER_A, bool DEG_BIAS, bool DEG_VIA_IDX, bool OUT_BF16, bool PROD_BATCH>
__global__ __launch_bounds__(256) void mfma_gemm(
    const __bf16* __restrict__ A_in,
    const __bf16* __restrict__ Wt_in,
    const float* __restrict__ biasD,
    void* __restrict__ Cout_in,
    const int* __restrict__ idx,
    const int* __restrict__ offs,
    int M)
{
    const __bf16* A  = A_in;
    const __bf16* Wt = Wt_in;
    void* Cout = Cout_in;
    if constexpr (PROD_BATCH) {
        const int z = blockIdx.z;
        A    = A_in  + (size_t)(3 * (1 + (z >> 1)) + (z & 1)) * WSZ;
        Wt   = Wt_in + (size_t)(z >> 1) * WSZ;
        Cout = (void*)((__bf16*)Cout_in + (size_t)z * WSZ);
    }

    __shared__ __bf16 As[64 * 32];
    __shared__ __bf16 Bs[128 * 32];
    __shared__ int s_idx[64];

    const int t    = threadIdx.x;
    const int lane = t & 63;
    const int wave = t >> 6;
    const int m0   = blockIdx.x * 64;
    const int n0   = blockIdx.y * 128;

    if constexpr (GATHER_A || DEG_VIA_IDX) {
        if (t < 64) s_idx[t] = idx[m0 + t];
        __syncthreads();
    }

    const int arow  = t >> 2;
    const int acol8 = (t & 3) * 8;
    int anode;
    if constexpr (GATHER_A) {
        anode = s_idx[arow];
    } else {
        const int rg = m0 + arow;
        anode = (rg < M) ? rg : (M - 1);
    }
    const __bf16* aptr = A + (size_t)anode * HIDDEN + acol8;

    const __bf16* bptr[2];
    #pragma unroll
    for (int r = 0; r < 2; ++r) {
        const int c = r * 256 + t;
        bptr[r] = Wt + (size_t)(n0 + (c >> 2)) * HIDDEN + (c & 3) * 8;
    }

    f32x4 acc[8];
    #pragma unroll
    for (int i = 0; i < 8; ++i) acc[i] = (f32x4){0.f, 0.f, 0.f, 0.f};

    const int wm   = wave * 16;
    const int fm   = lane & 15;
    const int quad = lane >> 4;

    for (int k0 = 0; k0 < HIDDEN; k0 += 32) {
        __syncthreads();
        load_lds16(aptr + k0, (void*)(As + (size_t)t * 8));
        #pragma unroll
        for (int r = 0; r < 2; ++r)
            load_lds16(bptr[r] + k0, (void*)(Bs + (size_t)(r * 256 + t) * 8));
        __syncthreads();

        const bf16x8 af = *(const bf16x8*)(As + (wm + fm) * 32 + quad * 8);
        bf16x8 bfr[8];
        #pragma unroll
        for (int nt = 0; nt < 8; ++nt)
            bfr[nt] = *(const bf16x8*)(Bs + (nt * 16 + fm) * 32 + quad * 8);

        #pragma unroll
        for (int nt = 0; nt < 8; ++nt)
            acc[nt] = __builtin_amdgcn_mfma_f32_16x16x32_bf16(
                af, bfr[nt], acc[nt], 0, 0, 0);
    }

    float bd[8];
    #pragma unroll
    for (int nt = 0; nt < 8; ++nt)
        bd[nt] = DEG_BIAS ? biasD[n0 + nt * 16 + fm] : 0.f;

    #pragma unroll
    for (int rg = 0; rg < 4; ++rg) {
        const int rloc = wm + quad * 4 + rg;
        const int orow = m0 + rloc;
        if (!PROD_BATCH && orow >= M) continue;
        int dnode = orow;
        if constexpr (GATHER_A || DEG_VIA_IDX) dnode = s_idx[rloc];
        float bscale = 0.f;
        if constexpr (DEG_BIAS)
            bscale = (float)(offs[dnode + 1] - offs[dnode]);
        #pragma unroll
        for (int nt = 0; nt < 8; ++nt) {
            const int col = n0 + nt * 16 + fm;
            float v = acc[nt][rg];
            if constexpr (DEG_BIAS) v += bscale * bd[nt];
            if constexpr (OUT_BF16)
                ((__bf16*)Cout)[(size_t)orow * HIDDEN + col] = (__bf16)v;
            else
                ((float*)Cout)[(size_t)orow * HIDDEN + col] = v;
        }
    }
}

// ---------------------------------------------------------------------------
// Weight prep, 12 z-slices in ONE launch (unchanged from R14).
// ---------------------------------------------------------------------------
__global__ __launch_bounds__(256) void wconv_kernel(
    const float* __restrict__ f0_w, const float* __restrict__ f1_w,
    const float* __restrict__ conv_w, const float* __restrict__ conv_b,
    __bf16* __restrict__ wt_all, __bf16* __restrict__ cw_nt,
    float* __restrict__ q)
{
    const int z = blockIdx.z;
    const int kx = blockIdx.x * 32, nx = blockIdx.y * 32;
    const int tx = threadIdx.x, ty = threadIdx.y;

    if (z < 9) {
        const int layer = z / 3, which = z % 3;
        const float* W = ((which == 0) ? f0_w : (which == 1) ? f1_w : conv_w)
                         + (size_t)layer * WSZ;
        __bf16* T = wt_all + (size_t)z * WSZ;

        __shared__ float tile[32][33];
        for (int i = ty; i < 32; i += 8)
            tile[i][tx] = W[(size_t)(kx + i) * HIDDEN + nx + tx];
        __syncthreads();
        for (int i = ty; i < 32; i += 8)
            T[(size_t)(nx + i) * HIDDEN + kx + tx] = (__bf16)tile[tx][i];
    } else if (z < 11) {
        const int layer = z - 9;
        const float* W = conv_w + (size_t)layer * WSZ;
        __bf16* T = cw_nt + (size_t)layer * WSZ;
        for (int i = ty; i < 32; i += 8)
            T[(size_t)(kx + i) * HIDDEN + nx + tx] =
                (__bf16)W[(size_t)(kx + i) * HIDDEN + nx + tx];
    } else {
        if (blockIdx.x >= 4 || blockIdx.y != 0) return;
        const int zq = blockIdx.x;
        const int l = zq >> 1, branch = zq & 1;
        const float* cb = conv_b + (size_t)l * HIDDEN;
        const float* W  = (branch ? f1_w : f0_w) + (size_t)(l + 1) * WSZ;
        const int n = ty * 32 + tx;
        float s = 0.f;
        #pragma unroll 4
        for (int k = 0; k < HIDDEN; ++k)
            s += cb[k] * W[(size_t)k * HIDDEN + n];
        q[(size_t)zq * HIDDEN + n] = s;
    }
}

// ---------------------------------------------------------------------------
// CSR build: histogram (+labeled-row flags) -> fused scan -> fill
// ---------------------------------------------------------------------------
__global__ __launch_bounds__(256) void hist_kernel(
    const int* __restrict__ dst, const int* __restrict__ pos,
    int* __restrict__ counts, int* __restrict__ flags)
{
    int e = blockIdx.x * 256 + threadIdx.x;
    if (e < N_EDGES) atomicAdd(&counts[dst[e]], 1);
    if (e < N_LABEL) flags[pos[e]] = 1;   // benign dup writes
}

__device__ __forceinline__ int block_incl_scan(int v, int* s, int t)
{
    s[t] = v; __syncthreads();
    #pragma unroll
    for (int off = 1; off < 256; off <<= 1) {
        int add = (t >= off) ? s[t - off] : 0;
        __syncthreads();
        s[t] += add;
        __syncthreads();
    }
    return s[t];
}

// Single-dispatch exclusive scan (R15-verified). 196 blocks co-resident on
// 256 CUs -> spin cannot deadlock. AGENT-scope atomics (per-XCD L2s not
// coherent, G16). bsum/ctr zeroed by launch-prefix memset (graph-safe).
__global__ __launch_bounds__(256) void scan_fused_kernel(
    const int* __restrict__ counts, int* __restrict__ offs,
    int* __restrict__ cursor, int* __restrict__ bsum, int* __restrict__ ctr)
{
    __shared__ int s[256];
    const int t = threadIdx.x;
    const int b = blockIdx.x;
    const int i = b * 256 + t;

    const int v    = counts[i];
    const int incl = block_incl_scan(v, s, t);
    const int excl = incl - v;
    const int total = s[255];
    __syncthreads();

    if (t == 0) {
        __hip_atomic_store(&bsum[b], total, __ATOMIC_RELEASE,
                           __HIP_MEMORY_SCOPE_AGENT);
        __hip_atomic_fetch_add(ctr, 1, __ATOMIC_ACQ_REL,
                               __HIP_MEMORY_SCOPE_AGENT);
        while (__hip_atomic_load(ctr, __ATOMIC_ACQUIRE,
                                 __HIP_MEMORY_SCOPE_AGENT) < SCAN_BLOCKS)
            __builtin_amdgcn_s_sleep(2);
    }
    __syncthreads();

    int pv = 0;
    if (t < b)
        pv = __hip_atomic_load(&bsum[t], __ATOMIC_ACQUIRE,
                               __HIP_MEMORY_SCOPE_AGENT);
    s[t] = pv; __syncthreads();
    #pragma unroll
    for (int off = 128; off >= 1; off >>= 1) {
        if (t < off) s[t] += s[t + off];
        __syncthreads();
    }
    const int o = excl + s[0];
    offs[i]   = o;
    cursor[i] = o;
}

__global__ __launch_bounds__(256) void fill_kernel(
    const int* __restrict__ src, const int* __restrict__ dst,
    int* __restrict__ cursor, int* __restrict__ src_sorted)
{
    int e = blockIdx.x * 256 + threadIdx.x;
    if (e < N_EDGES) {
        int p = atomicAdd(&cursor[dst[e]], 1);
        src_sorted[p] = src[e];
    }
}

// ---------------------------------------------------------------------------
// Pull-mode bf16 segment sum v5 — half-wave-per-dst + software pipelining.
// (R11-verified; structural random-gather ceiling ~57 us: 4 structures all
// land 56-65 us, FETCH pinned ~173 MB = 7x per-XCD L2 fill. Do not touch.)
// ---------------------------------------------------------------------------
template <bool COMPACT>
__global__ __launch_bounds__(256) void seg_sum5_kernel(
    const __bf16* __restrict__ x0,
    const int* __restrict__ srcs,
    const int* __restrict__ offs,
    const int* __restrict__ nodelist,
    __bf16* __restrict__ out)
{
    const int t    = threadIdx.x;
    const int wave = t >> 6;
    const int lane = t & 63;
    const int half = lane >> 5;
    const int li   = lane & 31;
    const int row  = blockIdx.x * 8 + wave * 2 + half;
    const int d    = COMPACT ? nodelist[row] : row;
    const int beg  = offs[d];
    const int deg  = offs[d + 1] - beg;
    const int hb   = half * 32;

    const __bf16* xs = x0 + li * 8;

    float a[8];
    #pragma unroll
    for (int k = 0; k < 8; ++k) a[k] = 0.f;

    for (int base = 0; base < deg; base += 32) {
        const int n = min(32, deg - base);
        int vs = 0;
        if (li < n) vs = srcs[beg + base + li];
        const int nv = n & ~3;

        bf16x8 c0, c1, c2, c3;
        if (nv) {
            const int s0 = __shfl(vs, hb + 0), s1 = __shfl(vs, hb + 1);
            const int s2 = __shfl(vs, hb + 2), s3 = __shfl(vs, hb + 3);
            c0 = *(const bf16x8*)(xs + (size_t)s0 * HIDDEN);
            c1 = *(const bf16x8*)(xs + (size_t)s1 * HIDDEN);
            c2 = *(const bf16x8*)(xs + (size_t)s2 * HIDDEN);
            c3 = *(const bf16x8*)(xs + (size_t)s3 * HIDDEN);
        }
        for (int j = 4; j + 4 <= nv; j += 4) {
            const int s0 = __shfl(vs, hb + j + 0), s1 = __shfl(vs, hb + j + 1);
            const int s2 = __shfl(vs, hb + j + 2), s3 = __shfl(vs, hb + j + 3);
            const bf16x8 n0 = *(const bf16x8*)(xs + (size_t)s0 * HIDDEN);
            const bf16x8 n1 = *(const bf16x8*)(xs + (size_t)s1 * HIDDEN);
            const bf16x8 n2 = *(const bf16x8*)(xs + (size_t)s2 * HIDDEN);
            const bf16x8 n3 = *(const bf16x8*)(xs + (size_t)s3 * HIDDEN);
            #pragma unroll
            for (int k = 0; k < 8; ++k)
                a[k] += (float)c0[k] + (float)c1[k] + (float)c2[k] + (float)c3[k];
            c0 = n0; c1 = n1; c2 = n2; c3 = n3;
        }
        if (nv) {
            #pragma unroll
            for (int k = 0; k < 8; ++k)
                a[k] += (float)c0[k] + (float)c1[k] + (float)c2[k] + (float)c3[k];
        }
        for (int j = nv; j < n; ++j) {
            const int s = __shfl(vs, hb + j);
            const bf16x8 v = *(const bf16x8*)(xs + (size_t)s * HIDDEN);
            #pragma unroll
            for (int k = 0; k < 8; ++k) a[k] += (float)v[k];
        }
    }

    bf16x8 o;
    #pragma unroll
    for (int k = 0; k < 8; ++k) o[k] = (__bf16)a[k];
    *(bf16x8*)(out + (size_t)row * HIDDEN + li * 8) = o;
}

extern "C" void kernel_launch(void* const* d_in, const int* in_sizes, int n_in,
                              void* d_out, int out_size, void* d_ws, size_t ws_size,
                              hipStream_t stream)
{
    const float* x       = (const float*)d_in[0];
    const float* f0_w    = (const float*)d_in[1];
    const float* f0_b    = (const float*)d_in[2];
    const float* f1_w    = (const float*)d_in[3];
    const float* f1_b    = (const float*)d_in[4];
    const float* conv_w  = (const float*)d_in[5];
    const float* conv_b  = (const float*)d_in[6];
    const int*   edge_src = (const int*)d_in[7];
    const int*   edge_dst = (const int*)d_in[8];
    const int*   pos      = (const int*)d_in[9];
    float* out = (float*)d_out;

    const size_t buf = (size_t)N_NODES * HIDDEN;   // 12.8M elems

    char* p = (char*)d_ws;
    __bf16* bufA   = (__bf16*)p; p += buf * 2;      // 25.6 MB
    __bf16* bufB   = (__bf16*)p; p += buf * 2;      // 25.6 MB
    __bf16* s_lbl  = (__bf16*)p; p += (size_t)N_LABEL * HIDDEN * 2;  // 4 MB
    __bf16* wt_all = (__bf16*)p; p += (size_t)9 * WSZ * 2;
    __bf16* prod   = (__bf16*)p; p += (size_t)4 * WSZ * 2;
    __bf16* cw_nt  = (__bf16*)p; p += (size_t)2 * WSZ * 2;
    float*  qv     = (float*)p;  p += (size_t)4 * HIDDEN * 4;
    // zeroed region: counts, flags, bsum, ctr (single memset)
    int* counts     = (int*)p;  p += NPAD * 4;     // reused as cursor
    int* flags      = (int*)p;  p += NPAD * 4;     // labeled-row bitmap
    int* bsum       = (int*)p;  p += 256 * 4;      // scan block totals
    int* ctr        = (int*)p;  p += 64 * 4;       // scan arrival counter
    int* offs       = (int*)p;  p += NPAD * 4;
    int* src_sorted = (int*)p;  p += (size_t)N_EDGES * 4;
    int* cursor = counts;       // counts dead after scan_fused reads them

    const int edge_blocks = (N_EDGES + 255) / 256;   // 3125

    // ---- CSR build + flags (one memset zeroes counts+flags+bsum+ctr) ----
    hipMemsetAsync(counts, 0, (2 * NPAD + 320) * sizeof(int), stream);
    hist_kernel<<<edge_blocks, 256, 0, stream>>>(edge_dst, pos, counts, flags);
    scan_fused_kernel<<<SCAN_BLOCKS, 256, 0, stream>>>(
        counts, offs, cursor, bsum, ctr);
    fill_kernel<<<edge_blocks, 256, 0, stream>>>(edge_src, edge_dst, cursor, src_sorted);

    // ---- weight prep: transpose (9) + straight Cw (2) + qprod, one launch ----
    wconv_kernel<<<dim3(8, 8, 12), dim3(32, 8), 0, stream>>>(
        f0_w, f1_w, conv_w, conv_b, wt_all, cw_nt, qv);

    // all 4 products prod_t[z] = (Cw_l · F_{l+1})^T in ONE batched launch
    mfma_gemm<false, false, false, true, true><<<dim3(4, 2, 4), 256, 0, stream>>>(
        wt_all, cw_nt, nullptr, prod, nullptr, nullptr, HIDDEN);

    const dim3 fused_grid(782, 2, 2);   // z=0 full (store-suppressed), z=1 label
    const dim3 lbl_grid(128, 2);

    __bf16* cur = bufA;              // S buffer (layer-0 GEMMs read x fp32)
    __bf16* tmp = bufB;

    for (int l = 0; l < N_LAYERS; ++l) {
        const float* B0 = f0_b + (size_t)l * HIDDEN;
        const float* B1 = f1_b + (size_t)l * HIDDEN;

        if (l == 0) {
            // x0 = x@F0_0+b0 (all, minus labeled) ∪ x@F1_0+b1 (labeled)
            mfma_gemm_fused<false, true><<<fused_grid, 256, 0, stream>>>(
                x, wt_all + 0 * WSZ, wt_all + 1 * WSZ,
                nullptr, nullptr, B0, B1, tmp, pos, offs, flags, N_NODES);
        } else {
            // x0 = S@(Cw·F0_l)+deg*q0+b0 ∪ S@(Cw·F1_l)+deg*q1+b1 (folded conv)
            const int z0 = (l - 1) * 2;
            mfma_gemm_fused<true, false><<<fused_grid, 256, 0, stream>>>(
                cur, prod + (size_t)z0 * WSZ, prod + (size_t)(z0 + 1) * WSZ,
                qv + (size_t)z0 * HIDDEN, qv + (size_t)(z0 + 1) * HIDDEN,
                B0, B1, tmp, pos, offs, flags, N_NODES);
        }

        if (l < N_LAYERS - 1) {
            // S = segment_sum(x0[src]) at ALL nodes (tmp -> cur)
            seg_sum5_kernel<false><<<N_NODES / 8, 256, 0, stream>>>(
                tmp, src_sorted, offs, nullptr, cur);
        } else {
            // S only at labeled dst nodes (tmp -> s_lbl, compact pos order)
            seg_sum5_kernel<true><<<N_LABEL / 8, 256, 0, stream>>>(
                tmp, src_sorted, offs, pos, s_lbl);
            // out[i] = S_lbl[i] @ Cw_2 + deg[pos[i]]*cb_2  -> d_out (fp32)
            // A sequential/compact (s_lbl), deg via idx (R13 lesson)
            mfma_gemm<false, true, true, false, false><<<lbl_grid, 256, 0, stream>>>(
                s_lbl, wt_all + (size_t)(2 * 3 + 2) * WSZ,
                conv_b + (size_t)2 * HIDDEN, out, pos, offs, N_LABEL);
        }
    }
}

// Round 17
// 418.870 us; speedup vs baseline: 1.0212x; 1.0128x over previous
//
#include <hip/hip_runtime.h>
#include <hip/hip_bf16.h>

#define N_NODES 50000
#define N_EDGES 800000
#define HIDDEN  256
#define N_LAYERS 3
#define N_PAIRS 4096
#define N_LABEL 8192            // 2*N_PAIRS labeled rows
#define NPAD    50176           // 196*256, padded node count for the scan
#define SCAN_BLOCKS (NPAD / 256) // 196
#define WSZ (HIDDEN * HIDDEN)    // 65536 elems per weight matrix

typedef __bf16 bf16x8 __attribute__((ext_vector_type(8)));
typedef __bf16 bf16x4 __attribute__((ext_vector_type(4)));
typedef float  f32x4  __attribute__((ext_vector_type(4)));

__device__ __forceinline__ void load_lds16(const void* g, void* l) {
    __builtin_amdgcn_global_load_lds(
        (const __attribute__((address_space(1))) void*)g,
        (__attribute__((address_space(3))) void*)l, 16, 0, 0);
}

// ---------------------------------------------------------------------------
// FUSED layer GEMM (R13/R14-verified best config): BK=32, 64x128 tile,
// 12.3 KB LDS (~13 blocks/CU; BK=64's 24 KB halved occupancy and regressed
// — R15/m132 lesson).  One launch does BOTH node linears of a layer:
//   blockIdx.z==0 : x0[r] = A[r]@Wt0^T (+deg*bD0) + bC0, stores SUPPRESSED
//                   on labeled rows (flags[r]!=0)
//   blockIdx.z==1 : x0[idx[r]] = A[idx[r]]@Wt1^T (+deg*bD1) + bC1
// Writes disjoint by construction -> race-free.
//   DEG_BIAS: add deg[orow]*bD[col] (orow IS the node id in both roles)
//   A_FP32  : A fp32, converted in-register during staging (layer 0)
// ---------------------------------------------------------------------------
template <bool DEG_BIAS, bool A_FP32>
__global__ __launch_bounds__(256) void mfma_gemm_fused(
    const void* __restrict__ A_in,
    const __bf16* __restrict__ Wt0, const __bf16* __restrict__ Wt1,
    const float* __restrict__ bD0, const float* __restrict__ bD1,
    const float* __restrict__ bC0, const float* __restrict__ bC1,
    __bf16* __restrict__ Cout,
    const int* __restrict__ idx,     // pos (labeled rows)
    const int* __restrict__ offs,
    const int* __restrict__ flags,   // 1 = labeled row
    int M)
{
    const int role = blockIdx.z;
    if (role == 1 && blockIdx.x >= N_LABEL / 64) return;

    const __bf16* A   = (const __bf16*)A_in;
    const float*  A32 = (const float*)A_in;
    const __bf16* Wt  = role ? Wt1 : Wt0;
    const float*  bD  = role ? bD1 : bD0;
    const float*  bC  = role ? bC1 : bC0;

    __shared__ __bf16 As[64 * 32];    // 4 KB
    __shared__ __bf16 Bs[128 * 32];   // 8 KB
    __shared__ int s_idx[64];

    const int t    = threadIdx.x;
    const int lane = t & 63;
    const int wave = t >> 6;
    const int m0   = blockIdx.x * 64;
    const int n0   = blockIdx.y * 128;

    if (role == 1) {
        if (t < 64) s_idx[t] = idx[m0 + t];
        __syncthreads();
    }

    // A staging: chunk t; row=t>>2, col8=(t&3)*8. B: chunks r*256+t.
    // LDS dest = chunk*16 B (wave-uniform base + lane*16: m104-safe)
    const int arow  = t >> 2;
    const int acol8 = (t & 3) * 8;
    int anode;
    if (role == 1) {
        anode = s_idx[arow];
    } else {
        const int rg = m0 + arow;
        anode = (rg < M) ? rg : (M - 1);   // clamp; stores guarded below
    }
    const __bf16* aptr   = A   + (size_t)anode * HIDDEN + acol8;
    const float*  aptr32 = A32 + (size_t)anode * HIDDEN + acol8;

    const __bf16* bptr[2];
    #pragma unroll
    for (int r = 0; r < 2; ++r) {
        const int c = r * 256 + t;
        bptr[r] = Wt + (size_t)(n0 + (c >> 2)) * HIDDEN + (c & 3) * 8;
    }

    f32x4 acc[8];
    #pragma unroll
    for (int i = 0; i < 8; ++i) acc[i] = (f32x4){0.f, 0.f, 0.f, 0.f};

    const int wm   = wave * 16;
    const int fm   = lane & 15;
    const int quad = lane >> 4;

    for (int k0 = 0; k0 < HIDDEN; k0 += 32) {
        __syncthreads();
        if constexpr (A_FP32) {
            const float* ap = aptr32 + k0;
            const float4 u0 = *(const float4*)(ap);
            const float4 u1 = *(const float4*)(ap + 4);
            bf16x8 w = {(__bf16)u0.x, (__bf16)u0.y, (__bf16)u0.z, (__bf16)u0.w,
                        (__bf16)u1.x, (__bf16)u1.y, (__bf16)u1.z, (__bf16)u1.w};
            *(bf16x8*)(As + (size_t)t * 8) = w;
        } else {
            load_lds16(aptr + k0, (void*)(As + (size_t)t * 8));
        }
        #pragma unroll
        for (int r = 0; r < 2; ++r)
            load_lds16(bptr[r] + k0, (void*)(Bs + (size_t)(r * 256 + t) * 8));
        __syncthreads();   // drains vmcnt+lgkmcnt: staged data visible

        const bf16x8 af = *(const bf16x8*)(As + (wm + fm) * 32 + quad * 8);
        bf16x8 bfr[8];
        #pragma unroll
        for (int nt = 0; nt < 8; ++nt)
            bfr[nt] = *(const bf16x8*)(Bs + (nt * 16 + fm) * 32 + quad * 8);

        #pragma unroll
        for (int nt = 0; nt < 8; ++nt)
            acc[nt] = __builtin_amdgcn_mfma_f32_16x16x32_bf16(
                af, bfr[nt], acc[nt], 0, 0, 0);
    }

    // epilogue: C/D layout col=lane&15, row=quad*4+reg (m89/m91-verified)
    float bd[8], bc[8];
    #pragma unroll
    for (int nt = 0; nt < 8; ++nt) {
        const int col = n0 + nt * 16 + fm;
        bd[nt] = DEG_BIAS ? bD[col] : 0.f;
        bc[nt] = bC[col];
    }

    #pragma unroll
    for (int rg = 0; rg < 4; ++rg) {
        const int rloc = wm + quad * 4 + rg;
        int orow;
        if (role == 1) {
            orow = s_idx[rloc];
        } else {
            orow = m0 + rloc;
            if (orow >= M) continue;
            if (flags[orow]) continue;     // labeled: z=1 writes this row
        }
        float bscale = 0.f;
        if constexpr (DEG_BIAS)
            bscale = (float)(offs[orow + 1] - offs[orow]);
        #pragma unroll
        for (int nt = 0; nt < 8; ++nt) {
            const int col = n0 + nt * 16 + fm;
            float v = acc[nt][rg];
            if constexpr (DEG_BIAS) v += bscale * bd[nt];
            v += bc[nt];
            Cout[(size_t)orow * HIDDEN + col] = (__bf16)v;
        }
    }
}

// ---------------------------------------------------------------------------
// Plain MFMA GEMM (product batch + final out GEMM).  64x128 tile, BK=32.
//   GATHER_A   : A-rows gathered via idx
//   DEG_VIA_IDX: A sequential/compact, deg via idx[rloc] (R13 NaN lesson)
// ---------------------------------------------------------------------------
template <bool GATHER_A, bool DEG_BIAS, bool DEG_VIA_IDX, bool OUT_BF16, bool PROD_BATCH>
__global__ __launch_bounds__(256) void mfma_gemm(
    const __bf16* __restrict__ A_in,
    const __bf16* __restrict__ Wt_in,
    const float* __restrict__ biasD,
    void* __restrict__ Cout_in,
    const int* __restrict__ idx,
    const int* __restrict__ offs,
    int M)
{
    const __bf16* A  = A_in;
    const __bf16* Wt = Wt_in;
    void* Cout = Cout_in;
    if constexpr (PROD_BATCH) {
        const int z = blockIdx.z;
        A    = A_in  + (size_t)(3 * (1 + (z >> 1)) + (z & 1)) * WSZ;
        Wt   = Wt_in + (size_t)(z >> 1) * WSZ;
        Cout = (void*)((__bf16*)Cout_in + (size_t)z * WSZ);
    }

    __shared__ __bf16 As[64 * 32];
    __shared__ __bf16 Bs[128 * 32];
    __shared__ int s_idx[64];

    const int t    = threadIdx.x;
    const int lane = t & 63;
    const int wave = t >> 6;
    const int m0   = blockIdx.x * 64;
    const int n0   = blockIdx.y * 128;

    if constexpr (GATHER_A || DEG_VIA_IDX) {
        if (t < 64) s_idx[t] = idx[m0 + t];
        __syncthreads();
    }

    const int arow  = t >> 2;
    const int acol8 = (t & 3) * 8;
    int anode;
    if constexpr (GATHER_A) {
        anode = s_idx[arow];
    } else {
        const int rg = m0 + arow;
        anode = (rg < M) ? rg : (M - 1);
    }
    const __bf16* aptr = A + (size_t)anode * HIDDEN + acol8;

    const __bf16* bptr[2];
    #pragma unroll
    for (int r = 0; r < 2; ++r) {
        const int c = r * 256 + t;
        bptr[r] = Wt + (size_t)(n0 + (c >> 2)) * HIDDEN + (c & 3) * 8;
    }

    f32x4 acc[8];
    #pragma unroll
    for (int i = 0; i < 8; ++i) acc[i] = (f32x4){0.f, 0.f, 0.f, 0.f};

    const int wm   = wave * 16;
    const int fm   = lane & 15;
    const int quad = lane >> 4;

    for (int k0 = 0; k0 < HIDDEN; k0 += 32) {
        __syncthreads();
        load_lds16(aptr + k0, (void*)(As + (size_t)t * 8));
        #pragma unroll
        for (int r = 0; r < 2; ++r)
            load_lds16(bptr[r] + k0, (void*)(Bs + (size_t)(r * 256 + t) * 8));
        __syncthreads();

        const bf16x8 af = *(const bf16x8*)(As + (wm + fm) * 32 + quad * 8);
        bf16x8 bfr[8];
        #pragma unroll
        for (int nt = 0; nt < 8; ++nt)
            bfr[nt] = *(const bf16x8*)(Bs + (nt * 16 + fm) * 32 + quad * 8);

        #pragma unroll
        for (int nt = 0; nt < 8; ++nt)
            acc[nt] = __builtin_amdgcn_mfma_f32_16x16x32_bf16(
                af, bfr[nt], acc[nt], 0, 0, 0);
    }

    float bd[8];
    #pragma unroll
    for (int nt = 0; nt < 8; ++nt)
        bd[nt] = DEG_BIAS ? biasD[n0 + nt * 16 + fm] : 0.f;

    #pragma unroll
    for (int rg = 0; rg < 4; ++rg) {
        const int rloc = wm + quad * 4 + rg;
        const int orow = m0 + rloc;
        if (!PROD_BATCH && orow >= M) continue;
        int dnode = orow;
        if constexpr (GATHER_A || DEG_VIA_IDX) dnode = s_idx[rloc];
        float bscale = 0.f;
        if constexpr (DEG_BIAS)
            bscale = (float)(offs[dnode + 1] - offs[dnode]);
        #pragma unroll
        for (int nt = 0; nt < 8; ++nt) {
            const int col = n0 + nt * 16 + fm;
            float v = acc[nt][rg];
            if constexpr (DEG_BIAS) v += bscale * bd[nt];
            if constexpr (OUT_BF16)
                ((__bf16*)Cout)[(size_t)orow * HIDDEN + col] = (__bf16)v;
            else
                ((float*)Cout)[(size_t)orow * HIDDEN + col] = v;
        }
    }
}

// ---------------------------------------------------------------------------
// Weight prep, 12 z-slices in ONE launch:
//  z 0..8 : T[z][n][k] = (bf16)W_z[k][n]   (transpose; z = layer*3 + which)
//  z 9..10: cw_nt[z-9] = (bf16)conv_w[z-9] (straight convert)
//  z 11   : qprod — blocks (x<4, y==0): q[x][n] = sum_k cb_l[k]*W[k][n]
// ---------------------------------------------------------------------------
__global__ __launch_bounds__(256) void wconv_kernel(
    const float* __restrict__ f0_w, const float* __restrict__ f1_w,
    const float* __restrict__ conv_w, const float* __restrict__ conv_b,
    __bf16* __restrict__ wt_all, __bf16* __restrict__ cw_nt,
    float* __restrict__ q)
{
    const int z = blockIdx.z;
    const int kx = blockIdx.x * 32, nx = blockIdx.y * 32;
    const int tx = threadIdx.x, ty = threadIdx.y;

    if (z < 9) {
        const int layer = z / 3, which = z % 3;
        const float* W = ((which == 0) ? f0_w : (which == 1) ? f1_w : conv_w)
                         + (size_t)layer * WSZ;
        __bf16* T = wt_all + (size_t)z * WSZ;

        __shared__ float tile[32][33];
        for (int i = ty; i < 32; i += 8)
            tile[i][tx] = W[(size_t)(kx + i) * HIDDEN + nx + tx];
        __syncthreads();
        for (int i = ty; i < 32; i += 8)
            T[(size_t)(nx + i) * HIDDEN + kx + tx] = (__bf16)tile[tx][i];
    } else if (z < 11) {
        const int layer = z - 9;
        const float* W = conv_w + (size_t)layer * WSZ;
        __bf16* T = cw_nt + (size_t)layer * WSZ;
        for (int i = ty; i < 32; i += 8)
            T[(size_t)(kx + i) * HIDDEN + nx + tx] =
                (__bf16)W[(size_t)(kx + i) * HIDDEN + nx + tx];
    } else {
        if (blockIdx.x >= 4 || blockIdx.y != 0) return;
        const int zq = blockIdx.x;
        const int l = zq >> 1, branch = zq & 1;
        const float* cb = conv_b + (size_t)l * HIDDEN;
        const float* W  = (branch ? f1_w : f0_w) + (size_t)(l + 1) * WSZ;
        const int n = ty * 32 + tx;
        float s = 0.f;
        #pragma unroll 4
        for (int k = 0; k < HIDDEN; ++k)
            s += cb[k] * W[(size_t)k * HIDDEN + n];
        q[(size_t)zq * HIDDEN + n] = s;
    }
}

// ---------------------------------------------------------------------------
// CSR build: histogram (+labeled-row flags) -> 3-stage scan -> fill
// (R16 measured the single-dispatch spin-scan at +6 us vs this 3-kernel
//  version — cross-XCD atomic spins cost more than 2 dispatch gaps.)
// ---------------------------------------------------------------------------
__global__ __launch_bounds__(256) void hist_kernel(
    const int* __restrict__ dst, const int* __restrict__ pos,
    int* __restrict__ counts, int* __restrict__ flags)
{
    int e = blockIdx.x * 256 + threadIdx.x;
    if (e < N_EDGES) atomicAdd(&counts[dst[e]], 1);
    if (e < N_LABEL) flags[pos[e]] = 1;   // benign dup writes
}

__device__ __forceinline__ int block_incl_scan(int v, int* s, int t)
{
    s[t] = v; __syncthreads();
    #pragma unroll
    for (int off = 1; off < 256; off <<= 1) {
        int add = (t >= off) ? s[t - off] : 0;
        __syncthreads();
        s[t] += add;
        __syncthreads();
    }
    return s[t];
}

__global__ __launch_bounds__(256) void scan1_kernel(
    const int* __restrict__ counts, int* __restrict__ offs, int* __restrict__ bsum)
{
    __shared__ int s[256];
    const int t = threadIdx.x;
    const int i = blockIdx.x * 256 + t;
    const int v = counts[i];
    int incl = block_incl_scan(v, s, t);
    offs[i] = incl - v;
    if (t == 255) bsum[blockIdx.x] = incl;
}

__global__ __launch_bounds__(256) void scan2_kernel(
    const int* __restrict__ bsum, int* __restrict__ bbase)
{
    __shared__ int s[256];
    const int t = threadIdx.x;
    const int v = (t < SCAN_BLOCKS) ? bsum[t] : 0;
    int incl = block_incl_scan(v, s, t);
    bbase[t] = incl - v;
}

__global__ __launch_bounds__(256) void scan3_kernel(
    int* __restrict__ offs, const int* __restrict__ bbase, int* __restrict__ cursor)
{
    const int i = blockIdx.x * 256 + threadIdx.x;
    const int o = offs[i] + bbase[blockIdx.x];
    offs[i] = o;
    cursor[i] = o;
}

__global__ __launch_bounds__(256) void fill_kernel(
    const int* __restrict__ src, const int* __restrict__ dst,
    int* __restrict__ cursor, int* __restrict__ src_sorted)
{
    int e = blockIdx.x * 256 + threadIdx.x;
    if (e < N_EDGES) {
        int p = atomicAdd(&cursor[dst[e]], 1);
        src_sorted[p] = src[e];
    }
}

// ---------------------------------------------------------------------------
// Pull-mode bf16 segment sum v5 — half-wave-per-dst + software pipelining.
// (R11-verified; structural random-gather ceiling ~57 us: 5 structures all
// land 56-65 us, FETCH pinned ~173 MB = 7x per-XCD L2 fill. Do not touch.)
// ---------------------------------------------------------------------------
template <bool COMPACT>
__global__ __launch_bounds__(256) void seg_sum5_kernel(
    const __bf16* __restrict__ x0,
    const int* __restrict__ srcs,
    const int* __restrict__ offs,
    const int* __restrict__ nodelist,
    __bf16* __restrict__ out)
{
    const int t    = threadIdx.x;
    const int wave = t >> 6;
    const int lane = t & 63;
    const int half = lane >> 5;
    const int li   = lane & 31;
    const int row  = blockIdx.x * 8 + wave * 2 + half;
    const int d    = COMPACT ? nodelist[row] : row;
    const int beg  = offs[d];
    const int deg  = offs[d + 1] - beg;
    const int hb   = half * 32;

    const __bf16* xs = x0 + li * 8;

    float a[8];
    #pragma unroll
    for (int k = 0; k < 8; ++k) a[k] = 0.f;

    for (int base = 0; base < deg; base += 32) {
        const int n = min(32, deg - base);
        int vs = 0;
        if (li < n) vs = srcs[beg + base + li];
        const int nv = n & ~3;

        bf16x8 c0, c1, c2, c3;
        if (nv) {
            const int s0 = __shfl(vs, hb + 0), s1 = __shfl(vs, hb + 1);
            const int s2 = __shfl(vs, hb + 2), s3 = __shfl(vs, hb + 3);
            c0 = *(const bf16x8*)(xs + (size_t)s0 * HIDDEN);
            c1 = *(const bf16x8*)(xs + (size_t)s1 * HIDDEN);
            c2 = *(const bf16x8*)(xs + (size_t)s2 * HIDDEN);
            c3 = *(const bf16x8*)(xs + (size_t)s3 * HIDDEN);
        }
        for (int j = 4; j + 4 <= nv; j += 4) {
            const int s0 = __shfl(vs, hb + j + 0), s1 = __shfl(vs, hb + j + 1);
            const int s2 = __shfl(vs, hb + j + 2), s3 = __shfl(vs, hb + j + 3);
            const bf16x8 n0 = *(const bf16x8*)(xs + (size_t)s0 * HIDDEN);
            const bf16x8 n1 = *(const bf16x8*)(xs + (size_t)s1 * HIDDEN);
            const bf16x8 n2 = *(const bf16x8*)(xs + (size_t)s2 * HIDDEN);
            const bf16x8 n3 = *(const bf16x8*)(xs + (size_t)s3 * HIDDEN);
            #pragma unroll
            for (int k = 0; k < 8; ++k)
                a[k] += (float)c0[k] + (float)c1[k] + (float)c2[k] + (float)c3[k];
            c0 = n0; c1 = n1; c2 = n2; c3 = n3;
        }
        if (nv) {
            #pragma unroll
            for (int k = 0; k < 8; ++k)
                a[k] += (float)c0[k] + (float)c1[k] + (float)c2[k] + (float)c3[k];
        }
        for (int j = nv; j < n; ++j) {
            const int s = __shfl(vs, hb + j);
            const bf16x8 v = *(const bf16x8*)(xs + (size_t)s * HIDDEN);
            #pragma unroll
            for (int k = 0; k < 8; ++k) a[k] += (float)v[k];
        }
    }

    bf16x8 o;
    #pragma unroll
    for (int k = 0; k < 8; ++k) o[k] = (__bf16)a[k];
    *(bf16x8*)(out + (size_t)row * HIDDEN + li * 8) = o;
}

extern "C" void kernel_launch(void* const* d_in, const int* in_sizes, int n_in,
                              void* d_out, int out_size, void* d_ws, size_t ws_size,
                              hipStream_t stream)
{
    const float* x       = (const float*)d_in[0];
    const float* f0_w    = (const float*)d_in[1];
    const float* f0_b    = (const float*)d_in[2];
    const float* f1_w    = (const float*)d_in[3];
    const float* f1_b    = (const float*)d_in[4];
    const float* conv_w  = (const float*)d_in[5];
    const float* conv_b  = (const float*)d_in[6];
    const int*   edge_src = (const int*)d_in[7];
    const int*   edge_dst = (const int*)d_in[8];
    const int*   pos      = (const int*)d_in[9];
    float* out = (float*)d_out;

    const size_t buf = (size_t)N_NODES * HIDDEN;   // 12.8M elems

    char* p = (char*)d_ws;
    __bf16* bufA   = (__bf16*)p; p += buf * 2;      // 25.6 MB
    __bf16* bufB   = (__bf16*)p; p += buf * 2;      // 25.6 MB
    __bf16* s_lbl  = (__bf16*)p; p += (size_t)N_LABEL * HIDDEN * 2;  // 4 MB
    __bf16* wt_all = (__bf16*)p; p += (size_t)9 * WSZ * 2;
    __bf16* prod   = (__bf16*)p; p += (size_t)4 * WSZ * 2;
    __bf16* cw_nt  = (__bf16*)p; p += (size_t)2 * WSZ * 2;
    float*  qv     = (float*)p;  p += (size_t)4 * HIDDEN * 4;
    int* counts     = (int*)p;  p += NPAD * 4;     // reused as cursor
    int* flags      = (int*)p;  p += NPAD * 4;     // labeled-row bitmap
    int* offs       = (int*)p;  p += NPAD * 4;
    int* bsum       = (int*)p;  p += 256 * 4;
    int* bbase      = (int*)p;  p += 256 * 4;
    int* src_sorted = (int*)p;  p += (size_t)N_EDGES * 4;
    int* cursor = counts;       // counts dead after scan1

    const int edge_blocks = (N_EDGES + 255) / 256;   // 3125

    // ---- CSR build + flags (one memset covers counts+flags) ----
    hipMemsetAsync(counts, 0, 2 * NPAD * sizeof(int), stream);
    hist_kernel<<<edge_blocks, 256, 0, stream>>>(edge_dst, pos, counts, flags);
    scan1_kernel<<<SCAN_BLOCKS, 256, 0, stream>>>(counts, offs, bsum);
    scan2_kernel<<<1, 256, 0, stream>>>(bsum, bbase);
    scan3_kernel<<<SCAN_BLOCKS, 256, 0, stream>>>(offs, bbase, cursor);
    fill_kernel<<<edge_blocks, 256, 0, stream>>>(edge_src, edge_dst, cursor, src_sorted);

    // ---- weight prep: transpose (9) + straight Cw (2) + qprod, one launch ----
    wconv_kernel<<<dim3(8, 8, 12), dim3(32, 8), 0, stream>>>(
        f0_w, f1_w, conv_w, conv_b, wt_all, cw_nt, qv);

    // all 4 products prod_t[z] = (Cw_l · F_{l+1})^T in ONE batched launch
    mfma_gemm<false, false, false, true, true><<<dim3(4, 2, 4), 256, 0, stream>>>(
        wt_all, cw_nt, nullptr, prod, nullptr, nullptr, HIDDEN);

    const dim3 fused_grid(782, 2, 2);   // z=0 full (store-suppressed), z=1 label
    const dim3 lbl_grid(128, 2);

    __bf16* cur = bufA;              // S buffer (layer-0 GEMMs read x fp32)
    __bf16* tmp = bufB;

    for (int l = 0; l < N_LAYERS; ++l) {
        const float* B0 = f0_b + (size_t)l * HIDDEN;
        const float* B1 = f1_b + (size_t)l * HIDDEN;

        if (l == 0) {
            // x0 = x@F0_0+b0 (all, minus labeled) ∪ x@F1_0+b1 (labeled)
            mfma_gemm_fused<false, true><<<fused_grid, 256, 0, stream>>>(
                x, wt_all + 0 * WSZ, wt_all + 1 * WSZ,
                nullptr, nullptr, B0, B1, tmp, pos, offs, flags, N_NODES);
        } else {
            // x0 = S@(Cw·F0_l)+deg*q0+b0 ∪ S@(Cw·F1_l)+deg*q1+b1 (folded conv)
            const int z0 = (l - 1) * 2;
            mfma_gemm_fused<true, false><<<fused_grid, 256, 0, stream>>>(
                cur, prod + (size_t)z0 * WSZ, prod + (size_t)(z0 + 1) * WSZ,
                qv + (size_t)z0 * HIDDEN, qv + (size_t)(z0 + 1) * HIDDEN,
                B0, B1, tmp, pos, offs, flags, N_NODES);
        }

        if (l < N_LAYERS - 1) {
            // S = segment_sum(x0[src]) at ALL nodes (tmp -> cur)
            seg_sum5_kernel<false><<<N_NODES / 8, 256, 0, stream>>>(
                tmp, src_sorted, offs, nullptr, cur);
        } else {
            // S only at labeled dst nodes (tmp -> s_lbl, compact pos order)
            seg_sum5_kernel<true><<<N_LABEL / 8, 256, 0, stream>>>(
                tmp, src_sorted, offs, pos, s_lbl);
            // out[i] = S_lbl[i] @ Cw_2 + deg[pos[i]]*cb_2  -> d_out (fp32)
            // A sequential/compact (s_lbl), deg via idx (R13 lesson)
            mfma_gemm<false, true, true, false, false><<<lbl_grid, 256, 0, stream>>>(
                s_lbl, wt_all + (size_t)(2 * 3 + 2) * WSZ,
                conv_b + (size_t)2 * HIDDEN, out, pos, offs, N_LABEL);
        }
    }
}